// Round 7
// baseline (174.993 us; speedup 1.0000x reference)
//
#include <hip/hip_runtime.h>
#include <hip/hip_bf16.h>
#include <hip/hip_fp16.h>
#include <stdint.h>

#define M_DIM 4096   // B*S = 2*2048
#define N_DIM 4096   // O
#define K_DIM 4096   // I
#define GROUPSZ 128
#define MAXQ 15.0f

#define BM 256
#define BN 256
#define BK 64
#define T_TILES (K_DIM / BK)   // 64

typedef __attribute__((ext_vector_type(8))) short short8;
typedef __attribute__((ext_vector_type(4))) float f32x4;

// ---------------- quant: groupwise asymmetric fake-quant, f32 -> bf16 ----------------
__global__ __launch_bounds__(256) void quant_kernel(
    const float* __restrict__ weight, const float* __restrict__ value,
    const float* __restrict__ min_scale, const float* __restrict__ max_scale,
    __hip_bfloat16* __restrict__ wq)
{
    const int tid  = threadIdx.x;
    const int wave = tid >> 6;
    const int lane = tid & 63;
    const long g    = (long)blockIdx.x * 4 + wave;
    const long base = g * GROUPSZ + lane * 2;

    const float2 w = *(const float2*)(weight + base);
    const float2 v = *(const float2*)(value  + base);

    float mn = fminf(w.x, w.y);
    float mx = fmaxf(w.x, w.y);
#pragma unroll
    for (int off = 32; off >= 1; off >>= 1) {
        mn = fminf(mn, __shfl_xor(mn, off, 64));
        mx = fmaxf(mx, __shfl_xor(mx, off, 64));
    }
    mn = fminf(mn, 0.0f);
    mx = fmaxf(mx, 0.0f);

    const float ms = fminf(fmaxf(min_scale[g], -1.0f), 0.0f) + 1.0f;
    const float xs = fminf(fmaxf(max_scale[g], -1.0f), 0.0f) + 1.0f;
    float wmin = mn * ms;
    float wmax = mx * xs;
    if (wmin == 0.0f && wmax == 0.0f) { wmin = -1.0f; wmax = 1.0f; }

    const float scale = (float)(_Float16)((wmax - wmin) / MAXQ);
    const float zp    = rintf(-wmin / scale);

    const float q0 = fminf(fmaxf(rintf(w.x / scale + v.x) + zp, 0.0f), MAXQ);
    const float q1 = fminf(fmaxf(rintf(w.y / scale + v.y) + zp, 0.0f), MAXQ);
    const float o0 = scale * (q0 - zp);
    const float o1 = scale * (q1 - zp);

    __hip_bfloat162 o;
    o.x = __float2bfloat16(o0);
    o.y = __float2bfloat16(o1);
    *(__hip_bfloat162*)(wq + base) = o;
}

// ---------------- x cast: f32 -> bf16, 8 elems/thread ----------------
__global__ __launch_bounds__(256) void cast_kernel(
    const float* __restrict__ x, __hip_bfloat16* __restrict__ xb)
{
    const long i = ((long)blockIdx.x * 256 + threadIdx.x) * 8;
    const float4 a = *(const float4*)(x + i);
    const float4 b = *(const float4*)(x + i + 4);
    union { short8 s; __hip_bfloat16 h[8]; } u;
    u.h[0] = __float2bfloat16(a.x);
    u.h[1] = __float2bfloat16(a.y);
    u.h[2] = __float2bfloat16(a.z);
    u.h[3] = __float2bfloat16(a.w);
    u.h[4] = __float2bfloat16(b.x);
    u.h[5] = __float2bfloat16(b.y);
    u.h[6] = __float2bfloat16(b.z);
    u.h[7] = __float2bfloat16(b.w);
    *(short8*)(xb + i) = u.s;
}

// ---------------- GEMM: 256x256, BK=64, 8 waves, counted-vmcnt pipelined read-chain ----------------
// C[m][n] = sum_k A[m][k]*B[n][k] + bias[n]
// Stage-distance 2: S(t+2) issued at BAR2 of tile t (after all reads of buf c
// drained), entry wait is counted vmcnt(8) (S(t+1) stays in flight). The vmem
// queue never drains in the main loop; ds_reads chain under MFMA via counted lgkm.
__global__ __launch_bounds__(512, 2) void gemm_kernel(
    const __hip_bfloat16* __restrict__ A,   // [M][K] bf16 (x)
    const __hip_bfloat16* __restrict__ B,   // [N][K] bf16 (wq)
    const float* __restrict__ bias,
    float* __restrict__ C)                  // [M][N] f32
{
    __shared__ __align__(16) char lds[131072];
    // A buf c: [c*32768, +32768); B buf c: [65536 + c*32768, +32768)
    // row r at r*128 bytes; 16B slot s holds logical slot s ^ (r&7).

    const int tid  = threadIdx.x;
    const int lane = tid & 63;
    const int wv   = tid >> 6;
    const int wm   = wv >> 2;          // 2 (M) x 4 (N) wave grid
    const int wn   = wv & 3;

    const int bid = blockIdx.x;
    const int swz = (bid & 7) * (gridDim.x >> 3) + (bid >> 3);
    const int brow = (swz >> 4) * BM;
    const int bcol = (swz & 15) * BN;

    const int stg_r = tid >> 3;
    const int cc    = ((tid & 7) ^ (stg_r & 7)) * 8;

#define STAGE(XP, rowbase, h, tau, ldsbase)                                         \
    { _Pragma("unroll")                                                             \
      for (int inst = 0; inst < 2; ++inst) {                                        \
        const __hip_bfloat16* g = (XP) +                                            \
            (size_t)((rowbase) + (h) * 128 + inst * 64 + stg_r) * K_DIM +           \
            (tau) * 64 + cc;                                                        \
        __builtin_amdgcn_global_load_lds(                                           \
            (const __attribute__((address_space(1))) void*)g,                       \
            (__attribute__((address_space(3))) void*)(lds + (ldsbase) +             \
                (h) * 16384 + inst * 8192 + (wv << 10)),                            \
            16, 0, 0);                                                              \
      } }

    // stage one full K-tile (A+B halves) for tile tau into buffer bc (8 loads/wave)
#define STAGE_TILE(tau, bc)                                                         \
    STAGE(A, brow, 0, tau, (bc) * 32768);                                           \
    STAGE(A, brow, 1, tau, (bc) * 32768);                                           \
    STAGE(B, bcol, 0, tau, 65536 + (bc) * 32768);                                   \
    STAGE(B, bcol, 1, tau, 65536 + (bc) * 32768);

    const int ro = lane & 15;
    const int hi = lane >> 4;
    const int slot0 = ((0 + hi) ^ (ro & 7)) << 4;
    const int slot1 = ((4 + hi) ^ (ro & 7)) << 4;
    const int rbA = (wm * 128 + ro) * 128;
    const int rbB = (wn * 64  + ro) * 128;

    f32x4 acc[8][4] = {};

    // 16 MFMA: rows M0,M0+1 x 4 N x 2 kk, kk-outer (dep distance 8)
#define MFMA16(M0, X0, X1)                                                          \
    { _Pragma("unroll")                                                             \
      for (int n = 0; n < 4; ++n) {                                                 \
        acc[M0][n]     = __builtin_amdgcn_mfma_f32_16x16x32_bf16((X0)[0], bfr[n][0], acc[M0][n],     0, 0, 0); \
        acc[M0 + 1][n] = __builtin_amdgcn_mfma_f32_16x16x32_bf16((X1)[0], bfr[n][0], acc[M0 + 1][n], 0, 0, 0); \
      }                                                                             \
      _Pragma("unroll")                                                             \
      for (int n = 0; n < 4; ++n) {                                                 \
        acc[M0][n]     = __builtin_amdgcn_mfma_f32_16x16x32_bf16((X0)[1], bfr[n][1], acc[M0][n],     0, 0, 0); \
        acc[M0 + 1][n] = __builtin_amdgcn_mfma_f32_16x16x32_bf16((X1)[1], bfr[n][1], acc[M0 + 1][n], 0, 0, 0); \
      } }

#define LDA2(dst, m)                                                                \
    dst[0] = *(const short8*)(bA + (m) * 2048 + slot0);                             \
    dst[1] = *(const short8*)(bA + (m) * 2048 + slot1);

    // prologue: stage tile 0 -> buf0, tile 1 -> buf1 (16 loads in flight)
    STAGE_TILE(0, 0);
    STAGE_TILE(1, 1);

#pragma unroll 1
    for (int t = 0; t < T_TILES; ++t) {
        const int c = t & 1;
        const char* bA = lds + c * 32768 + rbA;
        const char* bB = lds + 65536 + c * 32768 + rbB;

        // entry: own S(t) done (S(t+1) stays in flight), then all waves' S(t) done
        if (t < T_TILES - 1) { asm volatile("s_waitcnt vmcnt(8)" ::: "memory"); }
        else                 { asm volatile("s_waitcnt vmcnt(0)" ::: "memory"); }
        __builtin_amdgcn_s_barrier();     // BAR1

        short8 bfr[4][2];
        short8 a0[2][2], a1[2][2], a2[2][2], a3[2][2];

        // top burst: all B (8) + A m0,m1 (4)
#pragma unroll
        for (int n = 0; n < 4; ++n) {
            bfr[n][0] = *(const short8*)(bB + n * 2048 + slot0);
            bfr[n][1] = *(const short8*)(bB + n * 2048 + slot1);
        }
        LDA2(a0[0], 0); LDA2(a0[1], 1);

        // chained reads: each cluster's operands issued one cluster early;
        // counted lgkmcnt leaves the newest 4 reads in flight under the MFMAs.
        LDA2(a1[0], 2); LDA2(a1[1], 3);
        asm volatile("s_waitcnt lgkmcnt(4)" ::: "memory");   // B,a0 done
        __builtin_amdgcn_sched_barrier(0);
        __builtin_amdgcn_s_setprio(1);
        MFMA16(0, a0[0], a0[1]);
        __builtin_amdgcn_s_setprio(0);

        LDA2(a2[0], 4); LDA2(a2[1], 5);
        asm volatile("s_waitcnt lgkmcnt(4)" ::: "memory");   // a1 done
        __builtin_amdgcn_sched_barrier(0);
        __builtin_amdgcn_s_setprio(1);
        MFMA16(2, a1[0], a1[1]);
        __builtin_amdgcn_s_setprio(0);

        LDA2(a3[0], 6); LDA2(a3[1], 7);
        asm volatile("s_waitcnt lgkmcnt(4)" ::: "memory");   // a2 done
        __builtin_amdgcn_sched_barrier(0);
        __builtin_amdgcn_s_setprio(1);
        MFMA16(4, a2[0], a2[1]);
        __builtin_amdgcn_s_setprio(0);

        asm volatile("s_waitcnt lgkmcnt(0)" ::: "memory");   // a3 done (all reads of buf c drained)
        __builtin_amdgcn_sched_barrier(0);
        __builtin_amdgcn_s_barrier();     // BAR2: every wave's reads of buf c done

        // stage tile t+2 into buf c (now provably free); flies for ~2 tiles
        if (t + 2 < T_TILES) { STAGE_TILE(t + 2, c); }

        __builtin_amdgcn_s_setprio(1);
        MFMA16(6, a3[0], a3[1]);
        __builtin_amdgcn_s_setprio(0);
    }

    // epilogue: C/D frag layout col = lane&15, row = hi*4 + reg
    const int col   = lane & 15;
    const int rbase = hi * 4;
    float bv[4];
#pragma unroll
    for (int n = 0; n < 4; ++n)
        bv[n] = bias[bcol + wn * 64 + n * 16 + col];

#pragma unroll
    for (int m = 0; m < 8; ++m) {
        const int mrow = brow + wm * 128 + m * 16 + rbase;
#pragma unroll
        for (int r = 0; r < 4; ++r) {
            float* crow = C + (size_t)(mrow + r) * N_DIM + bcol + wn * 64 + col;
#pragma unroll
            for (int n = 0; n < 4; ++n)
                crow[n * 16] = acc[m][n][r] + bv[n];
        }
    }
#undef STAGE
#undef STAGE_TILE
#undef MFMA16
#undef LDA2
}

extern "C" void kernel_launch(void* const* d_in, const int* in_sizes, int n_in,
                              void* d_out, int out_size, void* d_ws, size_t ws_size,
                              hipStream_t stream) {
    const float* x         = (const float*)d_in[0];
    const float* weight    = (const float*)d_in[1];
    const float* bias      = (const float*)d_in[2];
    const float* value     = (const float*)d_in[3];
    const float* min_scale = (const float*)d_in[4];
    const float* max_scale = (const float*)d_in[5];
    float* out = (float*)d_out;

    __hip_bfloat16* xb  = (__hip_bfloat16*)d_ws;                       // [M][K] bf16
    __hip_bfloat16* wqb = xb + (size_t)M_DIM * K_DIM;                  // [N][K] bf16

    quant_kernel<<<(N_DIM * K_DIM / GROUPSZ) / 4, 256, 0, stream>>>(
        weight, value, min_scale, max_scale, wqb);
    cast_kernel<<<(M_DIM * K_DIM) / (256 * 8), 256, 0, stream>>>(x, xb);
    gemm_kernel<<<(M_DIM / BM) * (N_DIM / BN), 512, 0, stream>>>(xb, wqb, bias, out);
}

// Round 8
// 170.295 us; speedup vs baseline: 1.0276x; 1.0276x over previous
//
#include <hip/hip_runtime.h>
#include <hip/hip_bf16.h>
#include <hip/hip_fp16.h>
#include <stdint.h>

#define M_DIM 4096   // B*S = 2*2048
#define N_DIM 4096   // O
#define K_DIM 4096   // I
#define GROUPSZ 128
#define MAXQ 15.0f

#define BM 256
#define BN 256
#define BK 64
#define T_TILES (K_DIM / BK)   // 64

typedef __attribute__((ext_vector_type(8))) short short8;
typedef __attribute__((ext_vector_type(4))) float f32x4;

// ---------------- quant: groupwise asymmetric fake-quant, f32 -> bf16 ----------------
__global__ __launch_bounds__(256) void quant_kernel(
    const float* __restrict__ weight, const float* __restrict__ value,
    const float* __restrict__ min_scale, const float* __restrict__ max_scale,
    __hip_bfloat16* __restrict__ wq)
{
    const int tid  = threadIdx.x;
    const int wave = tid >> 6;
    const int lane = tid & 63;
    const long g    = (long)blockIdx.x * 4 + wave;
    const long base = g * GROUPSZ + lane * 2;

    const float2 w = *(const float2*)(weight + base);
    const float2 v = *(const float2*)(value  + base);

    float mn = fminf(w.x, w.y);
    float mx = fmaxf(w.x, w.y);
#pragma unroll
    for (int off = 32; off >= 1; off >>= 1) {
        mn = fminf(mn, __shfl_xor(mn, off, 64));
        mx = fmaxf(mx, __shfl_xor(mx, off, 64));
    }
    mn = fminf(mn, 0.0f);
    mx = fmaxf(mx, 0.0f);

    const float ms = fminf(fmaxf(min_scale[g], -1.0f), 0.0f) + 1.0f;
    const float xs = fminf(fmaxf(max_scale[g], -1.0f), 0.0f) + 1.0f;
    float wmin = mn * ms;
    float wmax = mx * xs;
    if (wmin == 0.0f && wmax == 0.0f) { wmin = -1.0f; wmax = 1.0f; }

    const float scale = (float)(_Float16)((wmax - wmin) / MAXQ);
    const float zp    = rintf(-wmin / scale);

    const float q0 = fminf(fmaxf(rintf(w.x / scale + v.x) + zp, 0.0f), MAXQ);
    const float q1 = fminf(fmaxf(rintf(w.y / scale + v.y) + zp, 0.0f), MAXQ);
    const float o0 = scale * (q0 - zp);
    const float o1 = scale * (q1 - zp);

    __hip_bfloat162 o;
    o.x = __float2bfloat16(o0);
    o.y = __float2bfloat16(o1);
    *(__hip_bfloat162*)(wq + base) = o;
}

// ---------------- x cast: f32 -> bf16, 8 elems/thread ----------------
__global__ __launch_bounds__(256) void cast_kernel(
    const float* __restrict__ x, __hip_bfloat16* __restrict__ xb)
{
    const long i = ((long)blockIdx.x * 256 + threadIdx.x) * 8;
    const float4 a = *(const float4*)(x + i);
    const float4 b = *(const float4*)(x + i + 4);
    union { short8 s; __hip_bfloat16 h[8]; } u;
    u.h[0] = __float2bfloat16(a.x);
    u.h[1] = __float2bfloat16(a.y);
    u.h[2] = __float2bfloat16(a.z);
    u.h[3] = __float2bfloat16(a.w);
    u.h[4] = __float2bfloat16(b.x);
    u.h[5] = __float2bfloat16(b.y);
    u.h[6] = __float2bfloat16(b.z);
    u.h[7] = __float2bfloat16(b.w);
    *(short8*)(xb + i) = u.s;
}

// ---------------- GEMM: 256x256, BK=64, 8 waves, cross-tile read-prefetch chain ----------------
// C[m][n] = sum_k A[m][k]*B[n][k] + bias[n]
// B(t+1)+A01(t+1) fragments are read at the TAIL of tile t (from the other,
// already-resident buffer), so tile t+1's first MFMA cluster starts without a
// read burst in front of it. One barrier per tile; counted lgkm chain; the
// vmem queue drains only at a point issued a full tile earlier.
__global__ __launch_bounds__(512, 2) void gemm_kernel(
    const __hip_bfloat16* __restrict__ A,   // [M][K] bf16 (x)
    const __hip_bfloat16* __restrict__ B,   // [N][K] bf16 (wq)
    const float* __restrict__ bias,
    float* __restrict__ C)                  // [M][N] f32
{
    __shared__ __align__(16) char lds[131072];
    // A buf c: [c*32768, +32768); B buf c: [65536 + c*32768, +32768)
    // row r at r*128 bytes; 16B slot s holds logical slot s ^ (r&7).

    const int tid  = threadIdx.x;
    const int lane = tid & 63;
    const int wv   = tid >> 6;
    const int wm   = wv >> 2;          // 2 (M) x 4 (N) wave grid
    const int wn   = wv & 3;

    const int bid = blockIdx.x;
    const int swz = (bid & 7) * (gridDim.x >> 3) + (bid >> 3);
    const int brow = (swz >> 4) * BM;
    const int bcol = (swz & 15) * BN;

    const int stg_r = tid >> 3;
    const int cc    = ((tid & 7) ^ (stg_r & 7)) * 8;

#define STAGE(XP, rowbase, h, tau, ldsbase)                                         \
    { _Pragma("unroll")                                                             \
      for (int inst = 0; inst < 2; ++inst) {                                        \
        const __hip_bfloat16* g = (XP) +                                            \
            (size_t)((rowbase) + (h) * 128 + inst * 64 + stg_r) * K_DIM +           \
            (tau) * 64 + cc;                                                        \
        __builtin_amdgcn_global_load_lds(                                           \
            (const __attribute__((address_space(1))) void*)g,                       \
            (__attribute__((address_space(3))) void*)(lds + (ldsbase) +             \
                (h) * 16384 + inst * 8192 + (wv << 10)),                            \
            16, 0, 0);                                                              \
      } }

    // stage one full K-tile (A+B halves) for tile tau into buffer bc (8 loads/wave)
#define STAGE_TILE(tau, bc)                                                         \
    STAGE(A, brow, 0, tau, (bc) * 32768);                                           \
    STAGE(A, brow, 1, tau, (bc) * 32768);                                           \
    STAGE(B, bcol, 0, tau, 65536 + (bc) * 32768);                                   \
    STAGE(B, bcol, 1, tau, 65536 + (bc) * 32768);

    const int ro = lane & 15;
    const int hi = lane >> 4;
    const int slot0 = ((0 + hi) ^ (ro & 7)) << 4;
    const int slot1 = ((4 + hi) ^ (ro & 7)) << 4;
    const int rbA = (wm * 128 + ro) * 128;
    const int rbB = (wn * 64  + ro) * 128;

    f32x4 acc[8][4] = {};

    // 16 MFMA: rows M0,M0+1 x 4 N x 2 kk, kk-outer (dep distance 8)
#define MFMA16(M0, X0, X1)                                                          \
    { _Pragma("unroll")                                                             \
      for (int n = 0; n < 4; ++n) {                                                 \
        acc[M0][n]     = __builtin_amdgcn_mfma_f32_16x16x32_bf16((X0)[0], bfr[n][0], acc[M0][n],     0, 0, 0); \
        acc[M0 + 1][n] = __builtin_amdgcn_mfma_f32_16x16x32_bf16((X1)[0], bfr[n][0], acc[M0 + 1][n], 0, 0, 0); \
      }                                                                             \
      _Pragma("unroll")                                                             \
      for (int n = 0; n < 4; ++n) {                                                 \
        acc[M0][n]     = __builtin_amdgcn_mfma_f32_16x16x32_bf16((X0)[1], bfr[n][1], acc[M0][n],     0, 0, 0); \
        acc[M0 + 1][n] = __builtin_amdgcn_mfma_f32_16x16x32_bf16((X1)[1], bfr[n][1], acc[M0 + 1][n], 0, 0, 0); \
      } }

#define LDA2(dst, m)                                                                \
    dst[0] = *(const short8*)(bA + (m) * 2048 + slot0);                             \
    dst[1] = *(const short8*)(bA + (m) * 2048 + slot1);

    short8 bfr[4][2];      // B(t) fragments, persistent across tiles
    short8 a0p[2][2];      // A m0,m1 of tile t, persistent

    // prologue: stage tile 0 -> buf0; drain; initial B(0)+A01(0) prefetch
    STAGE_TILE(0, 0);
    asm volatile("s_waitcnt vmcnt(0)" ::: "memory");
    __builtin_amdgcn_s_barrier();
    {
        const char* bB = lds + 65536 + rbB;
        const char* bA = lds + rbA;
#pragma unroll
        for (int n = 0; n < 4; ++n) {
            bfr[n][0] = *(const short8*)(bB + n * 2048 + slot0);
            bfr[n][1] = *(const short8*)(bB + n * 2048 + slot1);
        }
        LDA2(a0p[0], 0); LDA2(a0p[1], 1);
    }

#pragma unroll 1
    for (int t = 0; t < T_TILES; ++t) {
        const int c = t & 1;
        const char* bA = lds + c * 32768 + rbA;

        // stage next tile into the other buffer (safe: all waves' reads of that
        // buffer drained before the barrier at the end of tile t-1)
        if (t + 1 < T_TILES) { STAGE_TILE(t + 1, c ^ 1); }

        short8 a1[2][2], a2[2][2], a3[2][2];

        // entering: bfr(8) + a0p(4) outstanding; chain drains them at lgkm(4)
        LDA2(a1[0], 2); LDA2(a1[1], 3);
        asm volatile("s_waitcnt lgkmcnt(4)" ::: "memory");   // bfr,a0p done
        __builtin_amdgcn_sched_barrier(0);
        __builtin_amdgcn_s_setprio(1);
        MFMA16(0, a0p[0], a0p[1]);
        __builtin_amdgcn_s_setprio(0);

        LDA2(a2[0], 4); LDA2(a2[1], 5);
        asm volatile("s_waitcnt lgkmcnt(4)" ::: "memory");   // a1 done
        __builtin_amdgcn_sched_barrier(0);
        __builtin_amdgcn_s_setprio(1);
        MFMA16(2, a1[0], a1[1]);
        __builtin_amdgcn_s_setprio(0);

        LDA2(a3[0], 6); LDA2(a3[1], 7);
        asm volatile("s_waitcnt lgkmcnt(4)" ::: "memory");   // a2 done
        __builtin_amdgcn_sched_barrier(0);
        __builtin_amdgcn_s_setprio(1);
        MFMA16(4, a2[0], a2[1]);
        __builtin_amdgcn_s_setprio(0);

        asm volatile("s_waitcnt lgkmcnt(0)" ::: "memory");   // a3 done (last read of buf c)
        __builtin_amdgcn_sched_barrier(0);
        __builtin_amdgcn_s_setprio(1);
        MFMA16(6, a3[0], a3[1]);
        __builtin_amdgcn_s_setprio(0);

        // tail: prefetch next tile's B + A01 fragments from the other buffer.
        // vmcnt(0) drains S(t+1) (issued a full tile ago); barrier makes it
        // collective AND proves all waves' reads of buf c are done (each wave
        // passed lgkm(0) above) so next iteration may stage into buf c.
        if (t + 1 < T_TILES) {
            asm volatile("s_waitcnt vmcnt(0)" ::: "memory");
            __builtin_amdgcn_s_barrier();
            const char* bBn = lds + 65536 + (c ^ 1) * 32768 + rbB;
#pragma unroll
            for (int n = 0; n < 4; ++n) {
                bfr[n][0] = *(const short8*)(bBn + n * 2048 + slot0);
                bfr[n][1] = *(const short8*)(bBn + n * 2048 + slot1);
            }
            {
                const char* bA = lds + (c ^ 1) * 32768 + rbA;   // shadow for LDA2
                LDA2(a0p[0], 0); LDA2(a0p[1], 1);
            }
        }
    }

    // epilogue: C/D frag layout col = lane&15, row = hi*4 + reg
    const int col   = lane & 15;
    const int rbase = hi * 4;
    float bv[4];
#pragma unroll
    for (int n = 0; n < 4; ++n)
        bv[n] = bias[bcol + wn * 64 + n * 16 + col];

#pragma unroll
    for (int m = 0; m < 8; ++m) {
        const int mrow = brow + wm * 128 + m * 16 + rbase;
#pragma unroll
        for (int r = 0; r < 4; ++r) {
            float* crow = C + (size_t)(mrow + r) * N_DIM + bcol + wn * 64 + col;
#pragma unroll
            for (int n = 0; n < 4; ++n)
                crow[n * 16] = acc[m][n][r] + bv[n];
        }
    }
#undef STAGE
#undef STAGE_TILE
#undef MFMA16
#undef LDA2
}

extern "C" void kernel_launch(void* const* d_in, const int* in_sizes, int n_in,
                              void* d_out, int out_size, void* d_ws, size_t ws_size,
                              hipStream_t stream) {
    const float* x         = (const float*)d_in[0];
    const float* weight    = (const float*)d_in[1];
    const float* bias      = (const float*)d_in[2];
    const float* value     = (const float*)d_in[3];
    const float* min_scale = (const float*)d_in[4];
    const float* max_scale = (const float*)d_in[5];
    float* out = (float*)d_out;

    __hip_bfloat16* xb  = (__hip_bfloat16*)d_ws;                       // [M][K] bf16
    __hip_bfloat16* wqb = xb + (size_t)M_DIM * K_DIM;                  // [N][K] bf16

    quant_kernel<<<(N_DIM * K_DIM / GROUPSZ) / 4, 256, 0, stream>>>(
        weight, value, min_scale, max_scale, wqb);
    cast_kernel<<<(M_DIM * K_DIM) / (256 * 8), 256, 0, stream>>>(x, xb);
    gemm_kernel<<<(M_DIM / BM) * (N_DIM / BN), 512, 0, stream>>>(xb, wqb, bias, out);
}

// Round 9
// 167.869 us; speedup vs baseline: 1.0424x; 1.0145x over previous
//
#include <hip/hip_runtime.h>
#include <hip/hip_bf16.h>
#include <hip/hip_fp16.h>
#include <stdint.h>

#define M_DIM 4096   // B*S = 2*2048
#define N_DIM 4096   // O
#define K_DIM 4096   // I
#define GROUPSZ 128
#define MAXQ 15.0f

#define BM 256
#define BN 256
#define BK 64
#define T_TILES (K_DIM / BK)   // 64

typedef __attribute__((ext_vector_type(8))) short short8;
typedef __attribute__((ext_vector_type(4))) float f32x4;

// ---------------- quant: groupwise asymmetric fake-quant, f32 -> bf16 ----------------
__global__ __launch_bounds__(256) void quant_kernel(
    const float* __restrict__ weight, const float* __restrict__ value,
    const float* __restrict__ min_scale, const float* __restrict__ max_scale,
    __hip_bfloat16* __restrict__ wq)
{
    const int tid  = threadIdx.x;
    const int wave = tid >> 6;
    const int lane = tid & 63;
    const long g    = (long)blockIdx.x * 4 + wave;
    const long base = g * GROUPSZ + lane * 2;

    const float2 w = *(const float2*)(weight + base);
    const float2 v = *(const float2*)(value  + base);

    float mn = fminf(w.x, w.y);
    float mx = fmaxf(w.x, w.y);
#pragma unroll
    for (int off = 32; off >= 1; off >>= 1) {
        mn = fminf(mn, __shfl_xor(mn, off, 64));
        mx = fmaxf(mx, __shfl_xor(mx, off, 64));
    }
    mn = fminf(mn, 0.0f);
    mx = fmaxf(mx, 0.0f);

    const float ms = fminf(fmaxf(min_scale[g], -1.0f), 0.0f) + 1.0f;
    const float xs = fminf(fmaxf(max_scale[g], -1.0f), 0.0f) + 1.0f;
    float wmin = mn * ms;
    float wmax = mx * xs;
    if (wmin == 0.0f && wmax == 0.0f) { wmin = -1.0f; wmax = 1.0f; }

    const float scale = (float)(_Float16)((wmax - wmin) / MAXQ);
    const float zp    = rintf(-wmin / scale);

    const float q0 = fminf(fmaxf(rintf(w.x / scale + v.x) + zp, 0.0f), MAXQ);
    const float q1 = fminf(fmaxf(rintf(w.y / scale + v.y) + zp, 0.0f), MAXQ);
    const float o0 = scale * (q0 - zp);
    const float o1 = scale * (q1 - zp);

    __hip_bfloat162 o;
    o.x = __float2bfloat16(o0);
    o.y = __float2bfloat16(o1);
    *(__hip_bfloat162*)(wq + base) = o;
}

// ---------------- x cast: f32 -> bf16, 8 elems/thread ----------------
__global__ __launch_bounds__(256) void cast_kernel(
    const float* __restrict__ x, __hip_bfloat16* __restrict__ xb)
{
    const long i = ((long)blockIdx.x * 256 + threadIdx.x) * 8;
    const float4 a = *(const float4*)(x + i);
    const float4 b = *(const float4*)(x + i + 4);
    union { short8 s; __hip_bfloat16 h[8]; } u;
    u.h[0] = __float2bfloat16(a.x);
    u.h[1] = __float2bfloat16(a.y);
    u.h[2] = __float2bfloat16(a.z);
    u.h[3] = __float2bfloat16(a.w);
    u.h[4] = __float2bfloat16(b.x);
    u.h[5] = __float2bfloat16(b.y);
    u.h[6] = __float2bfloat16(b.z);
    u.h[7] = __float2bfloat16(b.w);
    *(short8*)(xb + i) = u.s;
}

// ---------------- GEMM: 256x256, BK=64, 8 waves, kk-major phases + tail prefetch ----------------
// C[m][n] = sum_k A[m][k]*B[n][k] + bias[n]
// Phases: P1 m0-3*kk0 (bfr0,afA)  P2 m4-7*kk0 (bfr0,afB)
//         P3 m0-3*kk1 (bfr1,afC)  P4 m4-7*kk1 (bfr1,afD)
// bfr0/afA die after P2/P1 -> the tail prefetch (next tile's bfr0+afA) is issued
// BEFORE P4 and drains under P4's MFMAs. One barrier/tile, counted lgkm chain.
__global__ __launch_bounds__(512, 2) void gemm_kernel(
    const __hip_bfloat16* __restrict__ A,   // [M][K] bf16 (x)
    const __hip_bfloat16* __restrict__ B,   // [N][K] bf16 (wq)
    const float* __restrict__ bias,
    float* __restrict__ C)                  // [M][N] f32
{
    __shared__ __align__(16) char lds[131072];
    // A buf c: [c*32768, +32768); B buf c: [65536 + c*32768, +32768)
    // row r at r*128 bytes; 16B slot s holds logical slot s ^ (r&7).

    const int tid  = threadIdx.x;
    const int lane = tid & 63;
    const int wv   = tid >> 6;
    const int wm   = wv >> 2;          // 2 (M) x 4 (N) wave grid
    const int wn   = wv & 3;

    const int bid = blockIdx.x;
    const int swz = (bid & 7) * (gridDim.x >> 3) + (bid >> 3);
    const int brow = (swz >> 4) * BM;
    const int bcol = (swz & 15) * BN;

    const int stg_r = tid >> 3;
    const int cc    = ((tid & 7) ^ (stg_r & 7)) * 8;

#define STAGE(XP, rowbase, h, tau, ldsbase)                                         \
    { _Pragma("unroll")                                                             \
      for (int inst = 0; inst < 2; ++inst) {                                        \
        const __hip_bfloat16* g = (XP) +                                            \
            (size_t)((rowbase) + (h) * 128 + inst * 64 + stg_r) * K_DIM +           \
            (tau) * 64 + cc;                                                        \
        __builtin_amdgcn_global_load_lds(                                           \
            (const __attribute__((address_space(1))) void*)g,                       \
            (__attribute__((address_space(3))) void*)(lds + (ldsbase) +             \
                (h) * 16384 + inst * 8192 + (wv << 10)),                            \
            16, 0, 0);                                                              \
      } }

#define STAGE_TILE(tau, bc)                                                         \
    STAGE(A, brow, 0, tau, (bc) * 32768);                                           \
    STAGE(A, brow, 1, tau, (bc) * 32768);                                           \
    STAGE(B, bcol, 0, tau, 65536 + (bc) * 32768);                                   \
    STAGE(B, bcol, 1, tau, 65536 + (bc) * 32768);

    const int ro = lane & 15;
    const int hi = lane >> 4;
    const int slot0 = ((0 + hi) ^ (ro & 7)) << 4;   // kk0
    const int slot1 = ((4 + hi) ^ (ro & 7)) << 4;   // kk1
    const int rbA = (wm * 128 + ro) * 128;
    const int rbB = (wn * 64  + ro) * 128;

    f32x4 acc[8][4] = {};

    // 16 independent MFMA: rows M0..M0+3 x 4 n at one kk (dep distance 16)
#define MFMA_C(M0, AF, BF)                                                          \
    { _Pragma("unroll")                                                             \
      for (int n = 0; n < 4; ++n) {                                                 \
        _Pragma("unroll")                                                           \
        for (int mm = 0; mm < 4; ++mm)                                              \
            acc[(M0) + mm][n] = __builtin_amdgcn_mfma_f32_16x16x32_bf16(            \
                AF[mm], BF[n], acc[(M0) + mm][n], 0, 0, 0);                         \
      } }

#define RDA4(dst, base, M0, S)                                                      \
    dst[0] = *(const short8*)((base) + ((M0) + 0) * 2048 + (S));                    \
    dst[1] = *(const short8*)((base) + ((M0) + 1) * 2048 + (S));                    \
    dst[2] = *(const short8*)((base) + ((M0) + 2) * 2048 + (S));                    \
    dst[3] = *(const short8*)((base) + ((M0) + 3) * 2048 + (S));

#define RDB4(dst, base, S)                                                          \
    dst[0] = *(const short8*)((base) + 0 * 2048 + (S));                             \
    dst[1] = *(const short8*)((base) + 1 * 2048 + (S));                             \
    dst[2] = *(const short8*)((base) + 2 * 2048 + (S));                             \
    dst[3] = *(const short8*)((base) + 3 * 2048 + (S));

    short8 bfr0[4], bfr1[4];             // B kk0 / kk1 fragments
    short8 afA[4], afB[4], afC[4], afD[4];  // A m0-3*kk0, m4-7*kk0, m0-3*kk1, m4-7*kk1

    // prologue: stage tile 0 -> buf0; drain; prefetch P1 operands (afA, bfr0)
    STAGE_TILE(0, 0);
    asm volatile("s_waitcnt vmcnt(0)" ::: "memory");
    __builtin_amdgcn_s_barrier();
    RDA4(afA, lds + rbA, 0, slot0);
    RDB4(bfr0, lds + 65536 + rbB, slot0);

#pragma unroll 1
    for (int t = 0; t < T_TILES; ++t) {
        const int c = t & 1;
        const char* bA  = lds + c * 32768 + rbA;
        const char* bB  = lds + 65536 + c * 32768 + rbB;
        const char* bAn = lds + (c ^ 1) * 32768 + rbA;
        const char* bBn = lds + 65536 + (c ^ 1) * 32768 + rbB;

        // stage next tile into the other buffer (WAR-safe: all waves' reads of
        // c^1 drained at their lgkm(0) before the tail barrier of tile t-1)
        if (t + 1 < T_TILES) { STAGE_TILE(t + 1, c ^ 1); }

        // entering: 8 outstanding DS (afA, bfr0 from tail of t-1)
        RDA4(afB, bA, 4, slot0);                             // -> 12
        RDB4(bfr1, bB, slot1);                               // -> 16
        asm volatile("s_waitcnt lgkmcnt(8)" ::: "memory");   // afA, bfr0 ready
        __builtin_amdgcn_sched_barrier(0);
        __builtin_amdgcn_s_setprio(1);
        MFMA_C(0, afA, bfr0);                                // P1
        __builtin_amdgcn_s_setprio(0);

        RDA4(afC, bA, 0, slot1);                             // -> <=12
        asm volatile("s_waitcnt lgkmcnt(8)" ::: "memory");   // afB ready
        __builtin_amdgcn_sched_barrier(0);
        __builtin_amdgcn_s_setprio(1);
        MFMA_C(4, afB, bfr0);                                // P2 (bfr0 dead after)
        __builtin_amdgcn_s_setprio(0);

        RDA4(afD, bA, 4, slot1);                             // -> <=12
        asm volatile("s_waitcnt lgkmcnt(4)" ::: "memory");   // bfr1, afC ready
        __builtin_amdgcn_sched_barrier(0);
        __builtin_amdgcn_s_setprio(1);
        MFMA_C(0, afC, bfr1);                                // P3
        __builtin_amdgcn_s_setprio(0);

        asm volatile("s_waitcnt lgkmcnt(0)" ::: "memory");   // afD ready; all buf-c reads done
        __builtin_amdgcn_sched_barrier(0);

        if (t + 1 < T_TILES) {
            asm volatile("s_waitcnt vmcnt(0)" ::: "memory"); // S(t+1) done (issued ~1 tile ago)
            __builtin_amdgcn_s_barrier();                    // all waves: reads done + stage visible
            // tail prefetch: next tile's P1 operands; drains UNDER P4
            RDA4(afA, bAn, 0, slot0);
            RDB4(bfr0, bBn, slot0);
            __builtin_amdgcn_sched_barrier(0);
        }

        __builtin_amdgcn_s_setprio(1);
        MFMA_C(4, afD, bfr1);                                // P4
        __builtin_amdgcn_s_setprio(0);
    }

    // epilogue: C/D frag layout col = lane&15, row = hi*4 + reg
    const int col   = lane & 15;
    const int rbase = hi * 4;
    float bv[4];
#pragma unroll
    for (int n = 0; n < 4; ++n)
        bv[n] = bias[bcol + wn * 64 + n * 16 + col];

#pragma unroll
    for (int m = 0; m < 8; ++m) {
        const int mrow = brow + wm * 128 + m * 16 + rbase;
#pragma unroll
        for (int r = 0; r < 4; ++r) {
            float* crow = C + (size_t)(mrow + r) * N_DIM + bcol + wn * 64 + col;
#pragma unroll
            for (int n = 0; n < 4; ++n)
                crow[n * 16] = acc[m][n][r] + bv[n];
        }
    }
#undef STAGE
#undef STAGE_TILE
#undef MFMA_C
#undef RDA4
#undef RDB4
}

extern "C" void kernel_launch(void* const* d_in, const int* in_sizes, int n_in,
                              void* d_out, int out_size, void* d_ws, size_t ws_size,
                              hipStream_t stream) {
    const float* x         = (const float*)d_in[0];
    const float* weight    = (const float*)d_in[1];
    const float* bias      = (const float*)d_in[2];
    const float* value     = (const float*)d_in[3];
    const float* min_scale = (const float*)d_in[4];
    const float* max_scale = (const float*)d_in[5];
    float* out = (float*)d_out;

    __hip_bfloat16* xb  = (__hip_bfloat16*)d_ws;                       // [M][K] bf16
    __hip_bfloat16* wqb = xb + (size_t)M_DIM * K_DIM;                  // [N][K] bf16

    quant_kernel<<<(N_DIM * K_DIM / GROUPSZ) / 4, 256, 0, stream>>>(
        weight, value, min_scale, max_scale, wqb);
    cast_kernel<<<(M_DIM * K_DIM) / (256 * 8), 256, 0, stream>>>(x, xb);
    gemm_kernel<<<(M_DIM / BM) * (N_DIM / BN), 512, 0, stream>>>(xb, wqb, bias, out);
}